// Round 1
// baseline (499.191 us; speedup 1.0000x reference)
//
#include <hip/hip_runtime.h>
#include <math.h>

// Problem constants
#define BB 32
#define CC 122
#define TT 500
#define SS 13
#define WID 80
#define EMB 8
#define PROJ 1024
#define HID 768
#define TP 96          // pooled time length: floor((496-17)/5)+1
#define K2 (WID*CC)    // 9760 conv2 reduction dim
#define EPSF 1e-5f
#define KSPLIT 16

// ---------------- workspace layout (float offsets) ----------------
#define OFF_E    ((size_t)0)            // (B,C,T)       1,952,000
#define OFF_H1   ((size_t)1952000)      // (B,K2,TP)    29,982,720
#define OFF_PART ((size_t)31934720)     // (KS,B,WID,TP) 3,932,160
#define OFF_Y2   ((size_t)35866880)     // (B,WID,TP)      245,760
#define OFF_Z    ((size_t)36112640)     // (B,HID)          24,576
#define OFF_Z1   ((size_t)36137216)     // (B,PROJ)         32,768
#define OFF_G    ((size_t)36169984)     // (B,PROJ)         32,768
#define OFF_Y    ((size_t)36202752)     // (B,PROJ)         32,768
#define OFF_WC   ((size_t)36235520)     // (WID,21)          1,680
#define OFF_B1F  ((size_t)36237200)     // (WID)                80
#define OFF_SC2  ((size_t)36237280)     // (WID)                80
#define OFF_SH2  ((size_t)36237360)     // (WID)                80

__device__ __forceinline__ float eluf(float x) {
    return x > 0.f ? x : expm1f(x);
}

// ---------------- prep: fold conv1+pool+bn1 into 21-tap filter; bn2 scale/shift ----
__global__ void k_prep(const float* __restrict__ conv1_w, const float* __restrict__ conv1_b,
                       const float* __restrict__ g1, const float* __restrict__ b1,
                       const float* __restrict__ m1, const float* __restrict__ v1,
                       const float* __restrict__ conv2_b, const float* __restrict__ g2,
                       const float* __restrict__ b2, const float* __restrict__ m2,
                       const float* __restrict__ v2,
                       float* __restrict__ wc2, float* __restrict__ bias1f,
                       float* __restrict__ scale2, float* __restrict__ shift2f) {
    int o = threadIdx.x;
    if (o < WID) {
        float s1 = g1[o] * rsqrtf(v1[o] + EPSF);
        float sh1 = b1[o] - m1[o] * s1;
        #pragma unroll
        for (int d = 0; d < 21; d++) {
            int klo = d - 16; if (klo < 0) klo = 0;
            int khi = d;      if (khi > 4) khi = 4;
            float acc = 0.f;
            for (int k = klo; k <= khi; k++) acc += conv1_w[o*5 + k];
            wc2[o*21 + d] = acc * s1 * (1.f/17.f);
        }
        bias1f[o] = conv1_b[o] * s1 + sh1;
        float s2 = g2[o] * rsqrtf(v2[o] + EPSF);
        scale2[o] = s2;
        shift2f[o] = conv2_b[o] * s2 + (b2[o] - m2[o] * s2);
    }
}

// ---------------- subject-specific einsum: out[b,c,t] = sum_s x[b,c,s]*W[sid,t,s] + b_sub[sid,t]
// GEMM NT per batch: 64x64 tile, 4x4 micro, Kt=16
__global__ __launch_bounds__(256) void k_einsum(const float* __restrict__ x,
                                                const int* __restrict__ sid,
                                                const float* __restrict__ W_sub,
                                                const float* __restrict__ b_sub,
                                                float* __restrict__ oute) {
    __shared__ float As[16][68];
    __shared__ float Bs[16][68];
    int b  = blockIdx.z;
    int c0 = blockIdx.y * 64, t0 = blockIdx.x * 64;
    int s  = sid[b];
    const float* A  = x + (size_t)b * CC * TT;
    const float* Wg = W_sub + (size_t)s * TT * TT;
    int tid = threadIdx.x;
    int tx = tid & 15, ty = tid >> 4;
    float acc[4][4] = {};
    for (int k0 = 0; k0 < TT; k0 += 16) {
        int lk = tx, lr = ty;
        #pragma unroll
        for (int r = 0; r < 4; r++) {
            int row = lr + r * 16;
            int kk = k0 + lk;
            int cc = c0 + row;
            float va = 0.f;
            if (cc < CC && kk < TT) va = A[(size_t)cc * TT + kk];
            As[lk][row] = va;
            int tt = t0 + row;
            float vb = 0.f;
            if (tt < TT && kk < TT) vb = Wg[(size_t)tt * TT + kk];
            Bs[lk][row] = vb;
        }
        __syncthreads();
        #pragma unroll
        for (int kk = 0; kk < 16; kk++) {
            float4 a4 = *(const float4*)&As[kk][ty * 4];
            float4 b4 = *(const float4*)&Bs[kk][tx * 4];
            float av[4] = {a4.x, a4.y, a4.z, a4.w};
            float bv[4] = {b4.x, b4.y, b4.z, b4.w};
            #pragma unroll
            for (int i = 0; i < 4; i++)
                #pragma unroll
                for (int j = 0; j < 4; j++)
                    acc[i][j] += av[i] * bv[j];
        }
        __syncthreads();
    }
    int tb = t0 + tx * 4;
    if (tb < TT) {   // 500 % 4 == 0 so full float4 fits whenever tb < 500
        const float* bg = b_sub + (size_t)s * TT;
        float4 bv = *(const float4*)&bg[tb];
        float bb[4] = {bv.x, bv.y, bv.z, bv.w};
        #pragma unroll
        for (int i = 0; i < 4; i++) {
            int cc = c0 + ty * 4 + i;
            if (cc < CC) {
                float4 o4 = make_float4(acc[i][0] + bb[0], acc[i][1] + bb[1],
                                        acc[i][2] + bb[2], acc[i][3] + bb[3]);
                *(float4*)&oute[((size_t)b * CC + cc) * TT + tb] = o4;
            }
        }
    }
}

// ---------------- conv1 + avgpool + bn1 + elu (folded 21-tap stride-5 filter) ----
// out h1[b][o*122+c][t]  (layout feeds conv2 K-dim contiguously)
__global__ __launch_bounds__(256) void k_convpool(const float* __restrict__ oute,
                                                  const float* __restrict__ wc2,
                                                  const float* __restrict__ bias1f,
                                                  float* __restrict__ h1) {
    __shared__ float e[TT];
    __shared__ float wcs[WID * 21];
    __shared__ float b1s[WID];
    int bc = blockIdx.x;
    int b = bc / CC, c = bc % CC;
    int tid = threadIdx.x;
    for (int i = tid; i < TT; i += 256) e[i] = oute[((size_t)b * CC + c) * TT + i];
    for (int i = tid; i < WID * 21; i += 256) wcs[i] = wc2[i];
    if (tid < WID) b1s[tid] = bias1f[tid];
    __syncthreads();
    for (int idx = tid; idx < WID * TP; idx += 256) {
        int o = idx / TP, t = idx % TP;
        float acc = b1s[o];
        int base = 5 * t;
        #pragma unroll
        for (int d = 0; d < 21; d++) acc += e[base + d] * wcs[o * 21 + d];
        acc = eluf(acc);
        h1[((size_t)(b * K2 + o * CC + c)) * TP + t] = acc;
    }
}

// ---------------- conv2 split-K GEMM: part[ks][b][o][t] = sum_{k in chunk} w2[o,k]*h1[b,k,t]
__global__ __launch_bounds__(256) void k_conv2(const float* __restrict__ h1,
                                               const float* __restrict__ w2,
                                               float* __restrict__ part) {
    __shared__ float As[16][84];
    __shared__ float Bs[16][96];
    int ks = blockIdx.x;   // 0..KSPLIT-1
    int b  = blockIdx.y;
    int tid = threadIdx.x;
    int tx = tid & 15, ty = tid >> 4;
    float acc[5][6] = {};
    const float* hb = h1 + (size_t)b * K2 * TP;
    for (int kt = ks; kt < K2 / 16; kt += KSPLIT) {
        int k0 = kt * 16;
        {
            int kk = tid & 15, obase = tid >> 4;
            #pragma unroll
            for (int j = 0; j < 5; j++) {
                int o = obase + j * 16;
                As[kk][o] = w2[(size_t)o * K2 + k0 + kk];
            }
        }
        for (int idx = tid; idx < 16 * 96; idx += 256) {
            int kk = idx / 96, t = idx % 96;
            Bs[kk][t] = hb[(size_t)(k0 + kk) * TP + t];
        }
        __syncthreads();
        #pragma unroll
        for (int kk = 0; kk < 16; kk++) {
            float av[5], bv[6];
            #pragma unroll
            for (int m = 0; m < 5; m++) av[m] = As[kk][ty * 5 + m];
            #pragma unroll
            for (int n = 0; n < 6; n++) bv[n] = Bs[kk][tx * 6 + n];
            #pragma unroll
            for (int m = 0; m < 5; m++)
                #pragma unroll
                for (int n = 0; n < 6; n++)
                    acc[m][n] += av[m] * bv[n];
        }
        __syncthreads();
    }
    float* pp = part + ((size_t)(ks * BB + b) * WID) * TP;
    #pragma unroll
    for (int m = 0; m < 5; m++) {
        int o = ty * 5 + m;
        #pragma unroll
        for (int n = 0; n < 6; n++) {
            int t = tx * 6 + n;
            pp[(size_t)o * TP + t] = acc[m][n];
        }
    }
}

// ---------------- reduce split-K partials + bn2 + elu -> y2[b][o][t]
__global__ __launch_bounds__(256) void k_reduce2(const float* __restrict__ part,
                                                 const float* __restrict__ scale2,
                                                 const float* __restrict__ shift2f,
                                                 float* __restrict__ y2) {
    int idx = blockIdx.x * 256 + threadIdx.x;
    if (idx >= BB * WID * TP) return;
    int o = (idx / TP) % WID;
    float acc = 0.f;
    #pragma unroll
    for (int ks = 0; ks < KSPLIT; ks++)
        acc += part[(size_t)ks * (BB * WID * TP) + idx];
    y2[idx] = eluf(acc * scale2[o] + shift2f[o]);
}

// ---------------- proj: z[b, t*8+e] = sum_i y2[b,i,t]*pw[e,i] + pb[e]
__global__ __launch_bounds__(768) void k_proj(const float* __restrict__ y2,
                                              const float* __restrict__ pw,
                                              const float* __restrict__ pb,
                                              float* __restrict__ z) {
    __shared__ float ly[WID * TP];  // 7680 floats
    __shared__ float lw[EMB * WID]; // 640
    int b = blockIdx.x, tid = threadIdx.x;
    for (int i = tid; i < WID * TP; i += 768) ly[i] = y2[(size_t)b * WID * TP + i];
    if (tid < EMB * WID) lw[tid] = pw[tid];
    __syncthreads();
    int t = tid >> 3, e = tid & 7;
    float acc = pb[e];
    #pragma unroll 8
    for (int i = 0; i < WID; i++) acc += ly[i * TP + t] * lw[e * WID + i];
    z[(size_t)b * HID + tid] = acc;
}

// ---------------- mlp1 + exact gelu
__global__ __launch_bounds__(256) void k_mlp1(const float* __restrict__ z,
                                              const float* __restrict__ w,
                                              const float* __restrict__ bias,
                                              float* __restrict__ z1,
                                              float* __restrict__ g) {
    __shared__ float zs[HID];
    int b = blockIdx.y, tid = threadIdx.x;
    for (int i = tid; i < HID; i += 256) zs[i] = z[(size_t)b * HID + i];
    __syncthreads();
    int p = blockIdx.x * 256 + tid;
    const float4* wr = (const float4*)(w + (size_t)p * HID);
    float acc = bias[p];
    #pragma unroll 4
    for (int k4 = 0; k4 < HID / 4; k4++) {
        float4 w4 = wr[k4];
        acc += zs[k4*4+0]*w4.x + zs[k4*4+1]*w4.y + zs[k4*4+2]*w4.z + zs[k4*4+3]*w4.w;
    }
    z1[(size_t)b * PROJ + p] = acc;
    g[(size_t)b * PROJ + p] = 0.5f * acc * (1.f + erff(acc * 0.70710678118654752f));
}

// ---------------- mlp2 + residual: y = z1 + (g @ w2^T + b2)
__global__ __launch_bounds__(256) void k_mlp2(const float* __restrict__ g,
                                              const float* __restrict__ z1,
                                              const float* __restrict__ w,
                                              const float* __restrict__ bias,
                                              float* __restrict__ y) {
    __shared__ float gs[PROJ];
    int b = blockIdx.y, tid = threadIdx.x;
    for (int i = tid; i < PROJ; i += 256) gs[i] = g[(size_t)b * PROJ + i];
    __syncthreads();
    int q = blockIdx.x * 256 + tid;
    const float4* wr = (const float4*)(w + (size_t)q * PROJ);
    float acc = bias[q];
    #pragma unroll 4
    for (int k4 = 0; k4 < PROJ / 4; k4++) {
        float4 w4 = wr[k4];
        acc += gs[k4*4+0]*w4.x + gs[k4*4+1]*w4.y + gs[k4*4+2]*w4.z + gs[k4*4+3]*w4.w;
    }
    y[(size_t)b * PROJ + q] = z1[(size_t)b * PROJ + q] + acc;
}

// ---------------- LayerNorm over 1024 per row -> d_out
__global__ __launch_bounds__(256) void k_ln(const float* __restrict__ y,
                                            const float* __restrict__ lg,
                                            const float* __restrict__ lb,
                                            float* __restrict__ out) {
    int b = blockIdx.x, tid = threadIdx.x;
    const float4* yr = (const float4*)(y + (size_t)b * PROJ);
    float4 v = yr[tid];
    float s  = v.x + v.y + v.z + v.w;
    float sq = v.x*v.x + v.y*v.y + v.z*v.z + v.w*v.w;
    #pragma unroll
    for (int off = 32; off > 0; off >>= 1) {
        s  += __shfl_down(s, off);
        sq += __shfl_down(sq, off);
    }
    __shared__ float ss[4], ssq[4];
    int wv = tid >> 6, lane = tid & 63;
    if (lane == 0) { ss[wv] = s; ssq[wv] = sq; }
    __syncthreads();
    __shared__ float smu, sinv;
    if (tid == 0) {
        float Sm = ss[0] + ss[1] + ss[2] + ss[3];
        float Sq = ssq[0] + ssq[1] + ssq[2] + ssq[3];
        float mu = Sm * (1.f / PROJ);
        float var = Sq * (1.f / PROJ) - mu * mu;
        smu = mu;
        sinv = rsqrtf(var + EPSF);
    }
    __syncthreads();
    float mu = smu, inv = sinv;
    float4 g4 = ((const float4*)lg)[tid];
    float4 b4 = ((const float4*)lb)[tid];
    float4 o4;
    o4.x = (v.x - mu) * inv * g4.x + b4.x;
    o4.y = (v.y - mu) * inv * g4.y + b4.y;
    o4.z = (v.z - mu) * inv * g4.z + b4.z;
    o4.w = (v.w - mu) * inv * g4.w + b4.w;
    ((float4*)(out + (size_t)b * PROJ))[tid] = o4;
}

extern "C" void kernel_launch(void* const* d_in, const int* in_sizes, int n_in,
                              void* d_out, int out_size, void* d_ws, size_t ws_size,
                              hipStream_t stream) {
    const float* x        = (const float*)d_in[0];
    const int*   sid      = (const int*)  d_in[1];
    const float* W_sub    = (const float*)d_in[2];
    const float* b_sub    = (const float*)d_in[3];
    const float* conv1_w  = (const float*)d_in[4];
    const float* conv1_b  = (const float*)d_in[5];
    const float* bn1_g    = (const float*)d_in[6];
    const float* bn1_b    = (const float*)d_in[7];
    const float* bn1_m    = (const float*)d_in[8];
    const float* bn1_v    = (const float*)d_in[9];
    const float* conv2_w  = (const float*)d_in[10];
    const float* conv2_b  = (const float*)d_in[11];
    const float* bn2_g    = (const float*)d_in[12];
    const float* bn2_b    = (const float*)d_in[13];
    const float* bn2_m    = (const float*)d_in[14];
    const float* bn2_v    = (const float*)d_in[15];
    const float* proj_w   = (const float*)d_in[16];
    const float* proj_b   = (const float*)d_in[17];
    const float* mlp1_w   = (const float*)d_in[18];
    const float* mlp1_b   = (const float*)d_in[19];
    const float* mlp2_w   = (const float*)d_in[20];
    const float* mlp2_b   = (const float*)d_in[21];
    const float* ln_g     = (const float*)d_in[22];
    const float* ln_b     = (const float*)d_in[23];
    float* out = (float*)d_out;
    float* ws  = (float*)d_ws;

    float* ws_e    = ws + OFF_E;
    float* ws_h1   = ws + OFF_H1;
    float* ws_part = ws + OFF_PART;
    float* ws_y2   = ws + OFF_Y2;
    float* ws_z    = ws + OFF_Z;
    float* ws_z1   = ws + OFF_Z1;
    float* ws_g    = ws + OFF_G;
    float* ws_y    = ws + OFF_Y;
    float* ws_wc   = ws + OFF_WC;
    float* ws_b1f  = ws + OFF_B1F;
    float* ws_sc2  = ws + OFF_SC2;
    float* ws_sh2  = ws + OFF_SH2;

    hipLaunchKernelGGL(k_prep, dim3(1), dim3(128), 0, stream,
                       conv1_w, conv1_b, bn1_g, bn1_b, bn1_m, bn1_v,
                       conv2_b, bn2_g, bn2_b, bn2_m, bn2_v,
                       ws_wc, ws_b1f, ws_sc2, ws_sh2);

    hipLaunchKernelGGL(k_einsum, dim3(8, 2, BB), dim3(256), 0, stream,
                       x, sid, W_sub, b_sub, ws_e);

    hipLaunchKernelGGL(k_convpool, dim3(BB * CC), dim3(256), 0, stream,
                       ws_e, ws_wc, ws_b1f, ws_h1);

    hipLaunchKernelGGL(k_conv2, dim3(KSPLIT, BB), dim3(256), 0, stream,
                       ws_h1, conv2_w, ws_part);

    hipLaunchKernelGGL(k_reduce2, dim3((BB * WID * TP + 255) / 256), dim3(256), 0, stream,
                       ws_part, ws_sc2, ws_sh2, ws_y2);

    hipLaunchKernelGGL(k_proj, dim3(BB), dim3(768), 0, stream,
                       ws_y2, proj_w, proj_b, ws_z);

    hipLaunchKernelGGL(k_mlp1, dim3(PROJ / 256, BB), dim3(256), 0, stream,
                       ws_z, mlp1_w, mlp1_b, ws_z1, ws_g);

    hipLaunchKernelGGL(k_mlp2, dim3(PROJ / 256, BB), dim3(256), 0, stream,
                       ws_g, ws_z1, mlp2_w, mlp2_b, ws_y);

    hipLaunchKernelGGL(k_ln, dim3(BB), dim3(256), 0, stream,
                       ws_y, ln_g, ln_b, out);
}

// Round 2
// 348.750 us; speedup vs baseline: 1.4314x; 1.4314x over previous
//
#include <hip/hip_runtime.h>
#include <math.h>

// Problem constants
#define BB 32
#define CC 122
#define TT 500
#define SS 13
#define WID 80
#define EMB 8
#define PROJ 1024
#define HID 768
#define TP 96          // pooled time length
#define EPSF 1e-5f
#define KSPLIT 16      // c-chunks of 8 -> 16 partials
#define PST 104        // p_lds row stride (bf16 elems): 208B, 16B-aligned, 2-way-bank (free)

typedef float f32x4 __attribute__((ext_vector_type(4)));
typedef __bf16 bf16x8 __attribute__((ext_vector_type(8)));
typedef unsigned short u16x8 __attribute__((ext_vector_type(8)));
union BF8 { u16x8 u; bf16x8 b; };

// float -> bf16 bits, round-to-nearest-even
__device__ __forceinline__ unsigned short f2bf(float f) {
    union { float f; unsigned u; } v; v.f = f;
    unsigned r = v.u + 0x7FFFu + ((v.u >> 16) & 1u);
    return (unsigned short)(r >> 16);
}

__device__ __forceinline__ float eluf(float x) {
    return x > 0.f ? x : expm1f(x);
}

// ---------------- workspace layout (float offsets) ----------------
#define OFF_E    ((size_t)0)            // oute (B,C,T) f32      1,952,000
#define OFF_XB   ((size_t)1952000)      // x_bf (B,128,512) bf16 -> 1,048,576 f
#define OFF_WB   ((size_t)3000576)      // W_bf (S,512,512) bf16 -> 1,703,936 f
#define OFF_W2P  ((size_t)4704512)      // W2p (C,80,96) bf16    ->   468,480 f
#define OFF_PART ((size_t)5172992)      // (KS,B,WID,TP) f32      3,932,160
#define OFF_Y2   ((size_t)9105152)      // (B,WID,TP)               245,760
#define OFF_Z    ((size_t)9350912)      // (B,HID)                   24,576
#define OFF_Z1   ((size_t)9375488)      // (B,PROJ)                  32,768
#define OFF_G    ((size_t)9408256)      // (B,PROJ)                  32,768
#define OFF_Y    ((size_t)9441024)      // (B,PROJ)                  32,768
#define OFF_WC   ((size_t)9473792)      // (WID,21)                   1,680
#define OFF_B1F  ((size_t)9475472)      // (WID)                         80
#define OFF_SC2  ((size_t)9475552)      // (WID)                         80
#define OFF_SH2  ((size_t)9475632)      // (WID)                         80

// pack region sizes (elements)
#define NPK_X  (2097152)   // 32*128*512
#define NPK_W  (3407872)   // 13*512*512
#define NPK_W2 (936960)    // 122*80*96
#define NPK_TOT (NPK_X + NPK_W + NPK_W2)

// ---------------- prep: fold conv1+pool+bn1 into 21-tap filter; bn2 scale/shift ----
__global__ void k_prep(const float* __restrict__ conv1_w, const float* __restrict__ conv1_b,
                       const float* __restrict__ g1, const float* __restrict__ b1,
                       const float* __restrict__ m1, const float* __restrict__ v1,
                       const float* __restrict__ conv2_b, const float* __restrict__ g2,
                       const float* __restrict__ b2, const float* __restrict__ m2,
                       const float* __restrict__ v2,
                       float* __restrict__ wc2, float* __restrict__ bias1f,
                       float* __restrict__ scale2, float* __restrict__ shift2f) {
    int o = threadIdx.x;
    if (o < WID) {
        float s1 = g1[o] * rsqrtf(v1[o] + EPSF);
        float sh1 = b1[o] - m1[o] * s1;
        #pragma unroll
        for (int d = 0; d < 21; d++) {
            int klo = d - 16; if (klo < 0) klo = 0;
            int khi = d;      if (khi > 4) khi = 4;
            float acc = 0.f;
            for (int k = klo; k <= khi; k++) acc += conv1_w[o*5 + k];
            wc2[o*21 + d] = acc * s1 * (1.f/17.f);
        }
        bias1f[o] = conv1_b[o] * s1 + sh1;
        float s2 = g2[o] * rsqrtf(v2[o] + EPSF);
        scale2[o] = s2;
        shift2f[o] = conv2_b[o] * s2 + (b2[o] - m2[o] * s2);
    }
}

// ---------------- pack x, W_sub, conv2_w into padded bf16 buffers ----------------
__global__ __launch_bounds__(256) void k_pack(const float* __restrict__ x,
                                              const float* __restrict__ W_sub,
                                              const float* __restrict__ conv2_w,
                                              unsigned short* __restrict__ xb,
                                              unsigned short* __restrict__ wb,
                                              unsigned short* __restrict__ w2p) {
    size_t idx = (size_t)blockIdx.x * 256 + threadIdx.x;
    if (idx >= (size_t)NPK_TOT) return;
    if (idx < NPK_X) {
        int s = idx & 511, c = (idx >> 9) & 127, b = idx >> 16;
        float v = (c < CC && s < TT) ? x[((size_t)b * CC + c) * TT + s] : 0.f;
        xb[idx] = f2bf(v);
    } else if (idx < NPK_X + NPK_W) {
        size_t j = idx - NPK_X;
        int s = j & 511, t = (j >> 9) & 511, sub = j >> 18;
        float v = (t < TT && s < TT) ? W_sub[((size_t)sub * TT + t) * TT + s] : 0.f;
        wb[j] = f2bf(v);
    } else {
        size_t j = idx - NPK_X - NPK_W;
        int o = j % 96;
        int op = (j / 96) % WID;  // o'
        int c = j / (96 * WID);
        float v = (o < WID) ? conv2_w[((size_t)op * WID + o) * CC + c] : 0.f;
        w2p[j] = f2bf(v);
    }
}

// ---------------- subject einsum via MFMA bf16: out[b,c,t] = sum_s x[b,c,s]*W[sid,t,s] + b_sub
// grid (8 t-tiles, 2 c-tiles, 32 b), 256 thr = 4 waves, per-wave 16c x 64t
__global__ __launch_bounds__(256) void k_einsum(const unsigned short* __restrict__ xb,
                                                const unsigned short* __restrict__ wb,
                                                const int* __restrict__ sid,
                                                const float* __restrict__ b_sub,
                                                float* __restrict__ oute) {
    int b = blockIdx.z, c0 = blockIdx.y * 64, t0 = blockIdx.x * 64;
    int s = sid[b];
    int tid = threadIdx.x, w = tid >> 6, l = tid & 63, lr = l & 15, lg = l >> 4;
    const unsigned short* Ar = xb + ((size_t)(b * 128 + c0 + w * 16 + lr)) * 512 + 8 * lg;
    const unsigned short* Bb = wb + (size_t)s * 512 * 512 + 8 * lg;
    f32x4 acc[4] = {};
    int trow[4];
    #pragma unroll
    for (int nt = 0; nt < 4; nt++) trow[nt] = t0 + nt * 16 + lr;
    for (int kb = 0; kb < 512; kb += 32) {
        BF8 af; af.u = *(const u16x8*)(Ar + kb);
        #pragma unroll
        for (int nt = 0; nt < 4; nt++) {
            BF8 bf; bf.u = *(const u16x8*)(Bb + (size_t)trow[nt] * 512 + kb);
            acc[nt] = __builtin_amdgcn_mfma_f32_16x16x32_bf16(af.b, bf.b, acc[nt], 0, 0, 0);
        }
    }
    // C/D layout: col(t) = lane&15, row(c) = (lane>>4)*4 + r
    int crow = c0 + w * 16 + 4 * lg;
    const float* bg = b_sub + (size_t)s * TT;
    #pragma unroll
    for (int nt = 0; nt < 4; nt++) {
        int t = t0 + nt * 16 + lr;
        if (t < TT) {
            float bias = bg[t];
            #pragma unroll
            for (int r = 0; r < 4; r++) {
                int c = crow + r;
                if (c < CC) oute[((size_t)b * CC + c) * TT + t] = acc[nt][r] + bias;
            }
        }
    }
}

// ---------------- fused convpool (FIR21 stride5 + bn1 + elu) -> conv2 MFMA split-K ----
// grid (16 chunks, 32 b), 256 thr. Per c: p[80][96] cooperatively in LDS (bf16),
// then per-wave MFMA accumulation over the chunk's 8 c's. Writes part[chunk][b][80][96].
__global__ __launch_bounds__(256) void k_fused(const float* __restrict__ oute,
                                               const float* __restrict__ wc2,
                                               const float* __restrict__ b1f,
                                               const unsigned short* __restrict__ w2p,
                                               float* __restrict__ part) {
    __shared__ float e_lds[TT];
    __shared__ unsigned short p_lds[96 * PST];
    int chunk = blockIdx.x, b = blockIdx.y;
    int tid = threadIdx.x, w = tid >> 6, l = tid & 63, lr = l & 15, lg = l >> 4;

    // p-compute identity: thread = (o, third); o's FIR coeffs in registers
    int po = tid % WID;
    int pthird = tid / WID;      // 0..2 valid (tid<240)
    bool pact = tid < 240;
    float wcr[21]; float pbias = 0.f;
    if (pact) {
        #pragma unroll
        for (int d = 0; d < 21; d++) wcr[d] = wc2[po * 21 + d];
        pbias = b1f[po];
    }
    // zero K-pad columns 80..95 of p_lds (read by kb=64 MFMA iter)
    for (int i = tid; i < 96 * 16; i += 256) p_lds[(i / 16) * PST + 80 + (i % 16)] = 0;

    int nnt = (w < 2) ? 2 : 1;   // waves 0,1 own 2 nt-columns; 2,3 own 1
    f32x4 acc[2][5] = {};

    for (int ci = 0; ci < 8; ci++) {
        int c = chunk * 8 + ci;
        bool cvalid = c < CC;
        if (cvalid && tid < 125)
            ((float4*)e_lds)[tid] = ((const float4*)(oute + ((size_t)b * CC + c) * TT))[tid];
        __syncthreads();
        if (cvalid && pact) {
            int tbase = pthird * 32;
            for (int g = 0; g < 8; g++) {
                float wv[36];
                const float4* ep = (const float4*)(e_lds + tbase * 5 + 20 * g);
                #pragma unroll
                for (int q = 0; q < 9; q++) {
                    float4 v = ep[q];
                    wv[4*q] = v.x; wv[4*q+1] = v.y; wv[4*q+2] = v.z; wv[4*q+3] = v.w;
                }
                #pragma unroll
                for (int j = 0; j < 4; j++) {
                    float a = pbias;
                    #pragma unroll
                    for (int d = 0; d < 21; d++) a = fmaf(wcr[d], wv[5*j + d], a);
                    a = eluf(a);
                    p_lds[(tbase + 4*g + j) * PST + po] = f2bf(a);
                }
            }
        }
        __syncthreads();
        if (cvalid) {
            const unsigned short* Ar = w2p + (size_t)c * WID * 96 + 8 * lg;
            #pragma unroll
            for (int kb = 0; kb < 96; kb += 32) {
                BF8 af[5];
                #pragma unroll
                for (int mt = 0; mt < 5; mt++)
                    af[mt].u = *(const u16x8*)(Ar + (size_t)(mt * 16 + lr) * 96 + kb);
                for (int nn = 0; nn < nnt; nn++) {
                    int nt = w + 4 * nn;
                    BF8 bf; bf.u = *(const u16x8*)(p_lds + (nt * 16 + lr) * PST + kb + 8 * lg);
                    #pragma unroll
                    for (int mt = 0; mt < 5; mt++)
                        acc[nn][mt] = __builtin_amdgcn_mfma_f32_16x16x32_bf16(af[mt].b, bf.b, acc[nn][mt], 0, 0, 0);
                }
            }
        }
    }
    // epilogue: part[chunk][b][o][t]
    float* pp = part + ((size_t)(chunk * BB + b) * WID) * TP;
    for (int nn = 0; nn < nnt; nn++) {
        int t = (w + 4 * nn) * 16 + lr;
        #pragma unroll
        for (int mt = 0; mt < 5; mt++) {
            int obase = mt * 16 + 4 * lg;
            #pragma unroll
            for (int r = 0; r < 4; r++)
                pp[(size_t)(obase + r) * TP + t] = acc[nn][mt][r];
        }
    }
}

// ---------------- reduce split-K partials + bn2 + elu -> y2[b][o][t]
__global__ __launch_bounds__(256) void k_reduce2(const float* __restrict__ part,
                                                 const float* __restrict__ scale2,
                                                 const float* __restrict__ shift2f,
                                                 float* __restrict__ y2) {
    int idx = blockIdx.x * 256 + threadIdx.x;
    if (idx >= BB * WID * TP) return;
    int o = (idx / TP) % WID;
    float acc = 0.f;
    #pragma unroll
    for (int ks = 0; ks < KSPLIT; ks++)
        acc += part[(size_t)ks * (BB * WID * TP) + idx];
    y2[idx] = eluf(acc * scale2[o] + shift2f[o]);
}

// ---------------- proj: z[b, t*8+e] = sum_i y2[b,i,t]*pw[e,i] + pb[e]
__global__ __launch_bounds__(768) void k_proj(const float* __restrict__ y2,
                                              const float* __restrict__ pw,
                                              const float* __restrict__ pb,
                                              float* __restrict__ z) {
    __shared__ float ly[WID * TP];
    __shared__ float lw[EMB * WID];
    int b = blockIdx.x, tid = threadIdx.x;
    for (int i = tid; i < WID * TP; i += 768) ly[i] = y2[(size_t)b * WID * TP + i];
    if (tid < EMB * WID) lw[tid] = pw[tid];
    __syncthreads();
    int t = tid >> 3, e = tid & 7;
    float acc = pb[e];
    #pragma unroll 8
    for (int i = 0; i < WID; i++) acc += ly[i * TP + t] * lw[e * WID + i];
    z[(size_t)b * HID + tid] = acc;
}

// ---------------- mlp1 + exact gelu
__global__ __launch_bounds__(256) void k_mlp1(const float* __restrict__ z,
                                              const float* __restrict__ w,
                                              const float* __restrict__ bias,
                                              float* __restrict__ z1,
                                              float* __restrict__ g) {
    __shared__ float zs[HID];
    int b = blockIdx.y, tid = threadIdx.x;
    for (int i = tid; i < HID; i += 256) zs[i] = z[(size_t)b * HID + i];
    __syncthreads();
    int p = blockIdx.x * 256 + tid;
    const float4* wr = (const float4*)(w + (size_t)p * HID);
    float acc = bias[p];
    #pragma unroll 4
    for (int k4 = 0; k4 < HID / 4; k4++) {
        float4 w4 = wr[k4];
        acc += zs[k4*4+0]*w4.x + zs[k4*4+1]*w4.y + zs[k4*4+2]*w4.z + zs[k4*4+3]*w4.w;
    }
    z1[(size_t)b * PROJ + p] = acc;
    g[(size_t)b * PROJ + p] = 0.5f * acc * (1.f + erff(acc * 0.70710678118654752f));
}

// ---------------- mlp2 + residual: y = z1 + (g @ w2^T + b2)
__global__ __launch_bounds__(256) void k_mlp2(const float* __restrict__ g,
                                              const float* __restrict__ z1,
                                              const float* __restrict__ w,
                                              const float* __restrict__ bias,
                                              float* __restrict__ y) {
    __shared__ float gs[PROJ];
    int b = blockIdx.y, tid = threadIdx.x;
    for (int i = tid; i < PROJ; i += 256) gs[i] = g[(size_t)b * PROJ + i];
    __syncthreads();
    int q = blockIdx.x * 256 + tid;
    const float4* wr = (const float4*)(w + (size_t)q * PROJ);
    float acc = bias[q];
    #pragma unroll 4
    for (int k4 = 0; k4 < PROJ / 4; k4++) {
        float4 w4 = wr[k4];
        acc += gs[k4*4+0]*w4.x + gs[k4*4+1]*w4.y + gs[k4*4+2]*w4.z + gs[k4*4+3]*w4.w;
    }
    y[(size_t)b * PROJ + q] = z1[(size_t)b * PROJ + q] + acc;
}

// ---------------- LayerNorm over 1024 per row -> d_out
__global__ __launch_bounds__(256) void k_ln(const float* __restrict__ y,
                                            const float* __restrict__ lg,
                                            const float* __restrict__ lb,
                                            float* __restrict__ out) {
    int b = blockIdx.x, tid = threadIdx.x;
    const float4* yr = (const float4*)(y + (size_t)b * PROJ);
    float4 v = yr[tid];
    float s  = v.x + v.y + v.z + v.w;
    float sq = v.x*v.x + v.y*v.y + v.z*v.z + v.w*v.w;
    #pragma unroll
    for (int off = 32; off > 0; off >>= 1) {
        s  += __shfl_down(s, off);
        sq += __shfl_down(sq, off);
    }
    __shared__ float ss[4], ssq[4];
    int wv = tid >> 6, lane = tid & 63;
    if (lane == 0) { ss[wv] = s; ssq[wv] = sq; }
    __syncthreads();
    __shared__ float smu, sinv;
    if (tid == 0) {
        float Sm = ss[0] + ss[1] + ss[2] + ss[3];
        float Sq = ssq[0] + ssq[1] + ssq[2] + ssq[3];
        float mu = Sm * (1.f / PROJ);
        float var = Sq * (1.f / PROJ) - mu * mu;
        smu = mu;
        sinv = rsqrtf(var + EPSF);
    }
    __syncthreads();
    float mu = smu, inv = sinv;
    float4 g4 = ((const float4*)lg)[tid];
    float4 b4 = ((const float4*)lb)[tid];
    float4 o4;
    o4.x = (v.x - mu) * inv * g4.x + b4.x;
    o4.y = (v.y - mu) * inv * g4.y + b4.y;
    o4.z = (v.z - mu) * inv * g4.z + b4.z;
    o4.w = (v.w - mu) * inv * g4.w + b4.w;
    ((float4*)(out + (size_t)b * PROJ))[tid] = o4;
}

extern "C" void kernel_launch(void* const* d_in, const int* in_sizes, int n_in,
                              void* d_out, int out_size, void* d_ws, size_t ws_size,
                              hipStream_t stream) {
    const float* x        = (const float*)d_in[0];
    const int*   sid      = (const int*)  d_in[1];
    const float* W_sub    = (const float*)d_in[2];
    const float* b_sub    = (const float*)d_in[3];
    const float* conv1_w  = (const float*)d_in[4];
    const float* conv1_b  = (const float*)d_in[5];
    const float* bn1_g    = (const float*)d_in[6];
    const float* bn1_b    = (const float*)d_in[7];
    const float* bn1_m    = (const float*)d_in[8];
    const float* bn1_v    = (const float*)d_in[9];
    const float* conv2_w  = (const float*)d_in[10];
    const float* conv2_b  = (const float*)d_in[11];
    const float* bn2_g    = (const float*)d_in[12];
    const float* bn2_b    = (const float*)d_in[13];
    const float* bn2_m    = (const float*)d_in[14];
    const float* bn2_v    = (const float*)d_in[15];
    const float* proj_w   = (const float*)d_in[16];
    const float* proj_b   = (const float*)d_in[17];
    const float* mlp1_w   = (const float*)d_in[18];
    const float* mlp1_b   = (const float*)d_in[19];
    const float* mlp2_w   = (const float*)d_in[20];
    const float* mlp2_b   = (const float*)d_in[21];
    const float* ln_g     = (const float*)d_in[22];
    const float* ln_b     = (const float*)d_in[23];
    float* out = (float*)d_out;
    float* ws  = (float*)d_ws;

    float* ws_e    = ws + OFF_E;
    unsigned short* ws_xb  = (unsigned short*)(ws + OFF_XB);
    unsigned short* ws_wb  = (unsigned short*)(ws + OFF_WB);
    unsigned short* ws_w2p = (unsigned short*)(ws + OFF_W2P);
    float* ws_part = ws + OFF_PART;
    float* ws_y2   = ws + OFF_Y2;
    float* ws_z    = ws + OFF_Z;
    float* ws_z1   = ws + OFF_Z1;
    float* ws_g    = ws + OFF_G;
    float* ws_y    = ws + OFF_Y;
    float* ws_wc   = ws + OFF_WC;
    float* ws_b1f  = ws + OFF_B1F;
    float* ws_sc2  = ws + OFF_SC2;
    float* ws_sh2  = ws + OFF_SH2;

    hipLaunchKernelGGL(k_prep, dim3(1), dim3(128), 0, stream,
                       conv1_w, conv1_b, bn1_g, bn1_b, bn1_m, bn1_v,
                       conv2_b, bn2_g, bn2_b, bn2_m, bn2_v,
                       ws_wc, ws_b1f, ws_sc2, ws_sh2);

    hipLaunchKernelGGL(k_pack, dim3((NPK_TOT + 255) / 256), dim3(256), 0, stream,
                       x, W_sub, conv2_w, ws_xb, ws_wb, ws_w2p);

    hipLaunchKernelGGL(k_einsum, dim3(8, 2, BB), dim3(256), 0, stream,
                       ws_xb, ws_wb, sid, b_sub, ws_e);

    hipLaunchKernelGGL(k_fused, dim3(KSPLIT, BB), dim3(256), 0, stream,
                       ws_e, ws_wc, ws_b1f, ws_w2p, ws_part);

    hipLaunchKernelGGL(k_reduce2, dim3((BB * WID * TP + 255) / 256), dim3(256), 0, stream,
                       ws_part, ws_sc2, ws_sh2, ws_y2);

    hipLaunchKernelGGL(k_proj, dim3(BB), dim3(768), 0, stream,
                       ws_y2, proj_w, proj_b, ws_z);

    hipLaunchKernelGGL(k_mlp1, dim3(PROJ / 256, BB), dim3(256), 0, stream,
                       ws_z, mlp1_w, mlp1_b, ws_z1, ws_g);

    hipLaunchKernelGGL(k_mlp2, dim3(PROJ / 256, BB), dim3(256), 0, stream,
                       ws_g, ws_z1, mlp2_w, mlp2_b, ws_y);

    hipLaunchKernelGGL(k_ln, dim3(BB), dim3(256), 0, stream,
                       ws_y, ln_g, ln_b, out);
}

// Round 3
// 297.066 us; speedup vs baseline: 1.6804x; 1.1740x over previous
//
#include <hip/hip_runtime.h>
#include <math.h>

// Problem constants
#define BB 32
#define CC 122
#define TT 500
#define SS 13
#define WID 80
#define EMB 8
#define PROJ 1024
#define HID 768
#define TP 96          // pooled time length
#define EPSF 1e-5f
#define KP 9760        // conv2 flat K' = 122*80 (no padding; 2 c's = 160 = 5*32)
#define KBN 305        // KP/32 kb-iterations
#define KSPLIT 16

typedef float f32x4 __attribute__((ext_vector_type(4)));
typedef __bf16 bf16x8 __attribute__((ext_vector_type(8)));
typedef unsigned short u16x8 __attribute__((ext_vector_type(8)));
union BF8 { u16x8 u; bf16x8 b; };

// float -> bf16 bits, round-to-nearest-even
__device__ __forceinline__ unsigned short f2bf(float f) {
    union { float f; unsigned u; } v; v.f = f;
    unsigned r = v.u + 0x7FFFu + ((v.u >> 16) & 1u);
    return (unsigned short)(r >> 16);
}

__device__ __forceinline__ float eluf(float x) {
    return x > 0.f ? x : expm1f(x);
}

// ---------------- workspace layout (float offsets) ----------------
#define OFF_E    ((size_t)0)            // oute (B,C,T) f32        1,952,000
#define OFF_XB   ((size_t)1952000)      // x_bf (B,128,512) bf16 -> 1,048,576 f
#define OFF_WB   ((size_t)3000576)      // W_bf (S,512,512) bf16 -> 1,703,936 f
#define OFF_W2P  ((size_t)4704512)      // w2p (80,9760) bf16    ->   390,400 f
#define OFF_P    ((size_t)5094912)      // p (B,96,9760) bf16    ->14,991,360 f
#define OFF_PART ((size_t)20086272)     // (KS,B,WID,TP) f32       3,932,160
#define OFF_Z    ((size_t)24018432)     // (B,HID)                    24,576
#define OFF_Z1   ((size_t)24043008)     // (B,PROJ)                   32,768
#define OFF_G    ((size_t)24075776)     // (B,PROJ)                   32,768
#define OFF_Y    ((size_t)24108544)     // (B,PROJ)                   32,768
#define OFF_WC   ((size_t)24141312)     // (WID,21)                    1,680
#define OFF_B1F  ((size_t)24142992)     // (WID)                          80
#define OFF_SC2  ((size_t)24143072)     // (WID)                          80
#define OFF_SH2  ((size_t)24143152)     // (WID)                          80

// pack region sizes (elements)
#define NPK_X  (2097152)   // 32*128*512
#define NPK_W  (3407872)   // 13*512*512
#define NPK_W2 (780800)    // 80*9760
#define NPK_TOT (NPK_X + NPK_W + NPK_W2)

// ---------------- pack (bf16 staging) + fused prep (block 0) ----------------
__global__ __launch_bounds__(256) void k_pack(const float* __restrict__ x,
                                              const float* __restrict__ W_sub,
                                              const float* __restrict__ conv2_w,
                                              const float* __restrict__ conv1_w, const float* __restrict__ conv1_b,
                                              const float* __restrict__ g1, const float* __restrict__ b1,
                                              const float* __restrict__ m1, const float* __restrict__ v1,
                                              const float* __restrict__ conv2_b, const float* __restrict__ g2,
                                              const float* __restrict__ b2, const float* __restrict__ m2,
                                              const float* __restrict__ v2,
                                              unsigned short* __restrict__ xb,
                                              unsigned short* __restrict__ wb,
                                              unsigned short* __restrict__ w2p,
                                              float* __restrict__ wc2, float* __restrict__ bias1f,
                                              float* __restrict__ scale2, float* __restrict__ shift2f) {
    if (blockIdx.x == 0) {
        int o = threadIdx.x;
        if (o < WID) {
            float s1 = g1[o] * rsqrtf(v1[o] + EPSF);
            float sh1 = b1[o] - m1[o] * s1;
            #pragma unroll
            for (int d = 0; d < 21; d++) {
                int klo = d - 16; if (klo < 0) klo = 0;
                int khi = d;      if (khi > 4) khi = 4;
                float acc = 0.f;
                for (int k = klo; k <= khi; k++) acc += conv1_w[o*5 + k];
                wc2[o*21 + d] = acc * s1 * (1.f/17.f);
            }
            bias1f[o] = conv1_b[o] * s1 + sh1;
            float s2 = g2[o] * rsqrtf(v2[o] + EPSF);
            scale2[o] = s2;
            shift2f[o] = conv2_b[o] * s2 + (b2[o] - m2[o] * s2);
        }
    }
    size_t idx = (size_t)blockIdx.x * 256 + threadIdx.x;
    if (idx >= (size_t)NPK_TOT) return;
    if (idx < NPK_X) {
        int s = idx & 511, c = (idx >> 9) & 127, b = idx >> 16;
        float v = (c < CC && s < TT) ? x[((size_t)b * CC + c) * TT + s] : 0.f;
        xb[idx] = f2bf(v);
    } else if (idx < NPK_X + NPK_W) {
        size_t j = idx - NPK_X;
        int s = j & 511, t = (j >> 9) & 511, sub = j >> 18;
        float v = (t < TT && s < TT) ? W_sub[((size_t)sub * TT + t) * TT + s] : 0.f;
        wb[j] = f2bf(v);
    } else {
        size_t j = idx - NPK_X - NPK_W;
        int o = (int)(j / KP);
        int k = (int)(j % KP);
        int c = k / WID, op = k % WID;
        float v = conv2_w[((size_t)(o * WID + op)) * CC + c];
        w2p[j] = f2bf(v);
    }
}

// ---------------- subject einsum via MFMA bf16: out[b,c,t] = sum_s x[b,c,s]*W[sid,t,s] + b_sub
__global__ __launch_bounds__(256) void k_einsum(const unsigned short* __restrict__ xb,
                                                const unsigned short* __restrict__ wb,
                                                const int* __restrict__ sid,
                                                const float* __restrict__ b_sub,
                                                float* __restrict__ oute) {
    int b = blockIdx.z, c0 = blockIdx.y * 64, t0 = blockIdx.x * 64;
    int s = sid[b];
    int tid = threadIdx.x, w = tid >> 6, l = tid & 63, lr = l & 15, lg = l >> 4;
    const unsigned short* Ar = xb + ((size_t)(b * 128 + c0 + w * 16 + lr)) * 512 + 8 * lg;
    const unsigned short* Bb = wb + (size_t)s * 512 * 512 + 8 * lg;
    f32x4 acc[4] = {};
    int trow[4];
    #pragma unroll
    for (int nt = 0; nt < 4; nt++) trow[nt] = t0 + nt * 16 + lr;
    for (int kb = 0; kb < 512; kb += 32) {
        BF8 af; af.u = *(const u16x8*)(Ar + kb);
        #pragma unroll
        for (int nt = 0; nt < 4; nt++) {
            BF8 bf; bf.u = *(const u16x8*)(Bb + (size_t)trow[nt] * 512 + kb);
            acc[nt] = __builtin_amdgcn_mfma_f32_16x16x32_bf16(af.b, bf.b, acc[nt], 0, 0, 0);
        }
    }
    int crow = c0 + w * 16 + 4 * lg;
    const float* bg = b_sub + (size_t)s * TT;
    #pragma unroll
    for (int nt = 0; nt < 4; nt++) {
        int t = t0 + nt * 16 + lr;
        if (t < TT) {
            float bias = bg[t];
            #pragma unroll
            for (int r = 0; r < 4; r++) {
                int c = crow + r;
                if (c < CC) oute[((size_t)b * CC + c) * TT + t] = acc[nt][r] + bias;
            }
        }
    }
}

// ---------------- FIR21 stride5 + bn1 + elu -> p[b][t][c*80+o'] bf16 ----------------
// grid (122 c, 32 b), 256 thr. launch_bounds(256,2): allow ~128 VGPR so the
// 36-float window + 21 coeffs stay in registers (round-2's 52-VGPR squeeze
// made the compiler re-read LDS per tap -> 146us).
__global__ __launch_bounds__(256, 2) void k_fir(const float* __restrict__ oute,
                                                const float* __restrict__ wc2,
                                                const float* __restrict__ b1f,
                                                unsigned short* __restrict__ p) {
    __shared__ float e_lds[TT];
    int c = blockIdx.x, b = blockIdx.y;
    int tid = threadIdx.x;
    if (tid < 125)
        ((float4*)e_lds)[tid] = ((const float4*)(oute + ((size_t)b * CC + c) * TT))[tid];
    __syncthreads();
    if (tid >= 240) return;
    int po = tid % WID, third = tid / WID;
    float wcr[21];
    #pragma unroll
    for (int d = 0; d < 21; d++) wcr[d] = wc2[po * 21 + d];
    float pbias = b1f[po];
    int tbase = third * 32;
    unsigned short* prow = p + ((size_t)b * TP) * KP + (size_t)c * WID + po;
    #pragma unroll 2
    for (int g = 0; g < 8; g++) {
        const float4* ep = (const float4*)(e_lds + tbase * 5 + 20 * g);
        float4 q0 = ep[0], q1 = ep[1], q2 = ep[2], q3 = ep[3], q4 = ep[4],
               q5 = ep[5], q6 = ep[6], q7 = ep[7], q8 = ep[8];
        float wv[36] = {q0.x,q0.y,q0.z,q0.w, q1.x,q1.y,q1.z,q1.w,
                        q2.x,q2.y,q2.z,q2.w, q3.x,q3.y,q3.z,q3.w,
                        q4.x,q4.y,q4.z,q4.w, q5.x,q5.y,q5.z,q5.w,
                        q6.x,q6.y,q6.z,q6.w, q7.x,q7.y,q7.z,q7.w,
                        q8.x,q8.y,q8.z,q8.w};
        #pragma unroll
        for (int j = 0; j < 4; j++) {
            float a = pbias;
            #pragma unroll
            for (int d = 0; d < 21; d++) a = fmaf(wcr[d], wv[5*j + d], a);
            a = eluf(a);
            prow[(size_t)(tbase + 4*g + j) * KP] = f2bf(a);
        }
    }
}

// ---------------- conv2 pure MFMA GEMM: part[ks][b][o][t] = sum_{k chunk} w2p[o,k] p[b,t,k]
// grid (16, 32), 384 thr = 6 waves; wave w owns n-tile (16 t), 5 m-tiles, no LDS/syncs.
__global__ __launch_bounds__(384) void k_conv2(const unsigned short* __restrict__ p,
                                               const unsigned short* __restrict__ w2p,
                                               float* __restrict__ part) {
    int chunk = blockIdx.x, b = blockIdx.y;
    int tid = threadIdx.x, w = tid >> 6, l = tid & 63, lr = l & 15, lg = l >> 4;
    int kb0 = (chunk * KBN) / KSPLIT;
    int kb1 = ((chunk + 1) * KBN) / KSPLIT;
    const unsigned short* Brow = p + ((size_t)(b * TP + w * 16 + lr)) * KP + 8 * lg;
    const unsigned short* Arow = w2p + (size_t)lr * KP + 8 * lg;
    f32x4 acc[5] = {};
    for (int kb = kb0; kb < kb1; kb++) {
        int ko = kb * 32;
        BF8 bf; bf.u = *(const u16x8*)(Brow + ko);
        #pragma unroll
        for (int mt = 0; mt < 5; mt++) {
            BF8 af; af.u = *(const u16x8*)(Arow + (size_t)mt * 16 * KP + ko);
            acc[mt] = __builtin_amdgcn_mfma_f32_16x16x32_bf16(af.b, bf.b, acc[mt], 0, 0, 0);
        }
    }
    float* pp = part + ((size_t)(chunk * BB + b) * WID) * TP;
    int t = w * 16 + lr;
    #pragma unroll
    for (int mt = 0; mt < 5; mt++) {
        int ob = mt * 16 + 4 * lg;
        #pragma unroll
        for (int r = 0; r < 4; r++)
            pp[(size_t)(ob + r) * TP + t] = acc[mt][r];
    }
}

// ---------------- reduce split-K + bn2 + elu (y2 stays in LDS) + proj -> z ----------------
__global__ __launch_bounds__(256) void k_redproj(const float* __restrict__ part,
                                                 const float* __restrict__ scale2,
                                                 const float* __restrict__ shift2f,
                                                 const float* __restrict__ pw,
                                                 const float* __restrict__ pb,
                                                 float* __restrict__ z) {
    __shared__ float ly[WID * TP];   // 7680
    __shared__ float lw[EMB * WID];  // 640
    int b = blockIdx.x, tid = threadIdx.x;
    for (int i = tid; i < EMB * WID; i += 256) lw[i] = pw[i];
    for (int i = tid; i < WID * TP; i += 256) {
        float acc = 0.f;
        #pragma unroll
        for (int ks = 0; ks < KSPLIT; ks++)
            acc += part[(size_t)(ks * BB + b) * (WID * TP) + i];
        int o = i / TP;
        ly[i] = eluf(acc * scale2[o] + shift2f[o]);
    }
    __syncthreads();
    #pragma unroll
    for (int rep = 0; rep < 3; rep++) {
        int j = tid + 256 * rep;
        int e = j & 7, t = j >> 3;
        float acc = pb[e];
        #pragma unroll 10
        for (int o = 0; o < WID; o++) acc = fmaf(ly[o * TP + t], lw[e * WID + o], acc);
        z[(size_t)b * HID + j] = acc;
    }
}

// ---------------- mlp1 + exact gelu
__global__ __launch_bounds__(256) void k_mlp1(const float* __restrict__ z,
                                              const float* __restrict__ w,
                                              const float* __restrict__ bias,
                                              float* __restrict__ z1,
                                              float* __restrict__ g) {
    __shared__ float zs[HID];
    int b = blockIdx.y, tid = threadIdx.x;
    for (int i = tid; i < HID; i += 256) zs[i] = z[(size_t)b * HID + i];
    __syncthreads();
    int pq = blockIdx.x * 256 + tid;
    const float4* wr = (const float4*)(w + (size_t)pq * HID);
    float acc = bias[pq];
    #pragma unroll 4
    for (int k4 = 0; k4 < HID / 4; k4++) {
        float4 w4 = wr[k4];
        acc += zs[k4*4+0]*w4.x + zs[k4*4+1]*w4.y + zs[k4*4+2]*w4.z + zs[k4*4+3]*w4.w;
    }
    z1[(size_t)b * PROJ + pq] = acc;
    g[(size_t)b * PROJ + pq] = 0.5f * acc * (1.f + erff(acc * 0.70710678118654752f));
}

// ---------------- mlp2 + residual: y = z1 + (g @ w2^T + b2)
__global__ __launch_bounds__(256) void k_mlp2(const float* __restrict__ g,
                                              const float* __restrict__ z1,
                                              const float* __restrict__ w,
                                              const float* __restrict__ bias,
                                              float* __restrict__ y) {
    __shared__ float gs[PROJ];
    int b = blockIdx.y, tid = threadIdx.x;
    for (int i = tid; i < PROJ; i += 256) gs[i] = g[(size_t)b * PROJ + i];
    __syncthreads();
    int q = blockIdx.x * 256 + tid;
    const float4* wr = (const float4*)(w + (size_t)q * PROJ);
    float acc = bias[q];
    #pragma unroll 4
    for (int k4 = 0; k4 < PROJ / 4; k4++) {
        float4 w4 = wr[k4];
        acc += gs[k4*4+0]*w4.x + gs[k4*4+1]*w4.y + gs[k4*4+2]*w4.z + gs[k4*4+3]*w4.w;
    }
    y[(size_t)b * PROJ + q] = z1[(size_t)b * PROJ + q] + acc;
}

// ---------------- LayerNorm over 1024 per row -> d_out
__global__ __launch_bounds__(256) void k_ln(const float* __restrict__ y,
                                            const float* __restrict__ lg,
                                            const float* __restrict__ lb,
                                            float* __restrict__ out) {
    int b = blockIdx.x, tid = threadIdx.x;
    const float4* yr = (const float4*)(y + (size_t)b * PROJ);
    float4 v = yr[tid];
    float s  = v.x + v.y + v.z + v.w;
    float sq = v.x*v.x + v.y*v.y + v.z*v.z + v.w*v.w;
    #pragma unroll
    for (int off = 32; off > 0; off >>= 1) {
        s  += __shfl_down(s, off);
        sq += __shfl_down(sq, off);
    }
    __shared__ float ss[4], ssq[4];
    int wv = tid >> 6, lane = tid & 63;
    if (lane == 0) { ss[wv] = s; ssq[wv] = sq; }
    __syncthreads();
    __shared__ float smu, sinv;
    if (tid == 0) {
        float Sm = ss[0] + ss[1] + ss[2] + ss[3];
        float Sq = ssq[0] + ssq[1] + ssq[2] + ssq[3];
        float mu = Sm * (1.f / PROJ);
        float var = Sq * (1.f / PROJ) - mu * mu;
        smu = mu;
        sinv = rsqrtf(var + EPSF);
    }
    __syncthreads();
    float mu = smu, inv = sinv;
    float4 g4 = ((const float4*)lg)[tid];
    float4 b4 = ((const float4*)lb)[tid];
    float4 o4;
    o4.x = (v.x - mu) * inv * g4.x + b4.x;
    o4.y = (v.y - mu) * inv * g4.y + b4.y;
    o4.z = (v.z - mu) * inv * g4.z + b4.z;
    o4.w = (v.w - mu) * inv * g4.w + b4.w;
    ((float4*)(out + (size_t)b * PROJ))[tid] = o4;
}

extern "C" void kernel_launch(void* const* d_in, const int* in_sizes, int n_in,
                              void* d_out, int out_size, void* d_ws, size_t ws_size,
                              hipStream_t stream) {
    const float* x        = (const float*)d_in[0];
    const int*   sid      = (const int*)  d_in[1];
    const float* W_sub    = (const float*)d_in[2];
    const float* b_sub    = (const float*)d_in[3];
    const float* conv1_w  = (const float*)d_in[4];
    const float* conv1_b  = (const float*)d_in[5];
    const float* bn1_g    = (const float*)d_in[6];
    const float* bn1_b    = (const float*)d_in[7];
    const float* bn1_m    = (const float*)d_in[8];
    const float* bn1_v    = (const float*)d_in[9];
    const float* conv2_w  = (const float*)d_in[10];
    const float* conv2_b  = (const float*)d_in[11];
    const float* bn2_g    = (const float*)d_in[12];
    const float* bn2_b    = (const float*)d_in[13];
    const float* bn2_m    = (const float*)d_in[14];
    const float* bn2_v    = (const float*)d_in[15];
    const float* proj_w   = (const float*)d_in[16];
    const float* proj_b   = (const float*)d_in[17];
    const float* mlp1_w   = (const float*)d_in[18];
    const float* mlp1_b   = (const float*)d_in[19];
    const float* mlp2_w   = (const float*)d_in[20];
    const float* mlp2_b   = (const float*)d_in[21];
    const float* ln_g     = (const float*)d_in[22];
    const float* ln_b     = (const float*)d_in[23];
    float* out = (float*)d_out;
    float* ws  = (float*)d_ws;

    float* ws_e    = ws + OFF_E;
    unsigned short* ws_xb  = (unsigned short*)(ws + OFF_XB);
    unsigned short* ws_wb  = (unsigned short*)(ws + OFF_WB);
    unsigned short* ws_w2p = (unsigned short*)(ws + OFF_W2P);
    unsigned short* ws_p   = (unsigned short*)(ws + OFF_P);
    float* ws_part = ws + OFF_PART;
    float* ws_z    = ws + OFF_Z;
    float* ws_z1   = ws + OFF_Z1;
    float* ws_g    = ws + OFF_G;
    float* ws_y    = ws + OFF_Y;
    float* ws_wc   = ws + OFF_WC;
    float* ws_b1f  = ws + OFF_B1F;
    float* ws_sc2  = ws + OFF_SC2;
    float* ws_sh2  = ws + OFF_SH2;

    hipLaunchKernelGGL(k_pack, dim3((NPK_TOT + 255) / 256), dim3(256), 0, stream,
                       x, W_sub, conv2_w,
                       conv1_w, conv1_b, bn1_g, bn1_b, bn1_m, bn1_v,
                       conv2_b, bn2_g, bn2_b, bn2_m, bn2_v,
                       ws_xb, ws_wb, ws_w2p,
                       ws_wc, ws_b1f, ws_sc2, ws_sh2);

    hipLaunchKernelGGL(k_einsum, dim3(8, 2, BB), dim3(256), 0, stream,
                       ws_xb, ws_wb, sid, b_sub, ws_e);

    hipLaunchKernelGGL(k_fir, dim3(CC, BB), dim3(256), 0, stream,
                       ws_e, ws_wc, ws_b1f, ws_p);

    hipLaunchKernelGGL(k_conv2, dim3(KSPLIT, BB), dim3(384), 0, stream,
                       ws_p, ws_w2p, ws_part);

    hipLaunchKernelGGL(k_redproj, dim3(BB), dim3(256), 0, stream,
                       ws_part, ws_sc2, ws_sh2, proj_w, proj_b, ws_z);

    hipLaunchKernelGGL(k_mlp1, dim3(PROJ / 256, BB), dim3(256), 0, stream,
                       ws_z, mlp1_w, mlp1_b, ws_z1, ws_g);

    hipLaunchKernelGGL(k_mlp2, dim3(PROJ / 256, BB), dim3(256), 0, stream,
                       ws_g, ws_z1, mlp2_w, mlp2_b, ws_y);

    hipLaunchKernelGGL(k_ln, dim3(BB), dim3(256), 0, stream,
                       ws_y, ln_g, ln_b, out);
}

// Round 4
// 258.601 us; speedup vs baseline: 1.9303x; 1.1487x over previous
//
#include <hip/hip_runtime.h>
#include <math.h>

// Problem constants
#define BB 32
#define CC 122
#define TT 500
#define SS 13
#define WID 80
#define EMB 8
#define PROJ 1024
#define HID 768
#define TP 96          // pooled time length
#define EPSF 1e-5f
#define KP 9760        // conv2 flat K' = 122*80
#define KBN 305        // KP/32 kb-iterations
#define KSPLIT 16

typedef float f32x4 __attribute__((ext_vector_type(4)));
typedef __bf16 bf16x8 __attribute__((ext_vector_type(8)));
typedef unsigned short u16x8 __attribute__((ext_vector_type(8)));
union BF8 { u16x8 u; bf16x8 b; };

// float -> bf16 bits, round-to-nearest-even
__device__ __forceinline__ unsigned short f2bf(float f) {
    union { float f; unsigned u; } v; v.f = f;
    unsigned r = v.u + 0x7FFFu + ((v.u >> 16) & 1u);
    return (unsigned short)(r >> 16);
}

// cheap ELU: for x<=0, exp(x)-1 via hw v_exp; |err| ~1e-7, invisible vs bf16 noise
__device__ __forceinline__ float eluf(float x) {
    return x > 0.f ? x : __expf(x) - 1.f;
}

// ---------------- workspace layout (float offsets) ----------------
#define OFF_E    ((size_t)0)            // oute (B,C,T) f32        1,952,000
#define OFF_XB   ((size_t)1952000)      // x_bf (B,128,512) bf16 -> 1,048,576 f
#define OFF_WB   ((size_t)3000576)      // W_bf (S,512,512) bf16 -> 1,703,936 f
#define OFF_W2P  ((size_t)4704512)      // w2p (80,9760) bf16    ->   390,400 f
#define OFF_P    ((size_t)5094912)      // p (B,96,9760) bf16    ->14,991,360 f
#define OFF_PART ((size_t)20086272)     // (KS,B,WID,TP) f32       3,932,160
#define OFF_Z    ((size_t)24018432)     // z_bf (B,HID) bf16          12,288 f
#define OFF_Z1   ((size_t)24043008)     // (B,PROJ) f32               32,768
#define OFF_G    ((size_t)24075776)     // g_bf (B,PROJ) bf16         16,384 f
#define OFF_Y    ((size_t)24108544)     // (B,PROJ) f32               32,768
#define OFF_WC   ((size_t)24141312)     // (WID,21)                    1,680
#define OFF_B1F  ((size_t)24142992)     // (WID)                          80
#define OFF_SC2  ((size_t)24143072)     // (WID)                          80
#define OFF_SH2  ((size_t)24143152)     // (WID)                          80

// pack region sizes (elements)
#define NPK_X  (2097152)   // 32*128*512
#define NPK_W  (3407872)   // 13*512*512
#define NPK_W2 (780800)    // 80*9760
#define NPK_TOT (NPK_X + NPK_W + NPK_W2)

// ---------------- pack (bf16 staging) + fused prep (block 0) ----------------
__global__ __launch_bounds__(256) void k_pack(const float* __restrict__ x,
                                              const float* __restrict__ W_sub,
                                              const float* __restrict__ conv2_w,
                                              const float* __restrict__ conv1_w, const float* __restrict__ conv1_b,
                                              const float* __restrict__ g1, const float* __restrict__ b1,
                                              const float* __restrict__ m1, const float* __restrict__ v1,
                                              const float* __restrict__ conv2_b, const float* __restrict__ g2,
                                              const float* __restrict__ b2, const float* __restrict__ m2,
                                              const float* __restrict__ v2,
                                              unsigned short* __restrict__ xb,
                                              unsigned short* __restrict__ wb,
                                              unsigned short* __restrict__ w2p,
                                              float* __restrict__ wc2, float* __restrict__ bias1f,
                                              float* __restrict__ scale2, float* __restrict__ shift2f) {
    if (blockIdx.x == 0) {
        int o = threadIdx.x;
        if (o < WID) {
            float s1 = g1[o] * rsqrtf(v1[o] + EPSF);
            float sh1 = b1[o] - m1[o] * s1;
            #pragma unroll
            for (int d = 0; d < 21; d++) {
                int klo = d - 16; if (klo < 0) klo = 0;
                int khi = d;      if (khi > 4) khi = 4;
                float acc = 0.f;
                for (int k = klo; k <= khi; k++) acc += conv1_w[o*5 + k];
                wc2[o*21 + d] = acc * s1 * (1.f/17.f);
            }
            bias1f[o] = conv1_b[o] * s1 + sh1;
            float s2 = g2[o] * rsqrtf(v2[o] + EPSF);
            scale2[o] = s2;
            shift2f[o] = conv2_b[o] * s2 + (b2[o] - m2[o] * s2);
        }
    }
    size_t idx = (size_t)blockIdx.x * 256 + threadIdx.x;
    if (idx >= (size_t)NPK_TOT) return;
    if (idx < NPK_X) {
        int s = idx & 511, c = (idx >> 9) & 127, b = idx >> 16;
        float v = (c < CC && s < TT) ? x[((size_t)b * CC + c) * TT + s] : 0.f;
        xb[idx] = f2bf(v);
    } else if (idx < NPK_X + NPK_W) {
        size_t j = idx - NPK_X;
        int s = j & 511, t = (j >> 9) & 511, sub = j >> 18;
        float v = (t < TT && s < TT) ? W_sub[((size_t)sub * TT + t) * TT + s] : 0.f;
        wb[j] = f2bf(v);
    } else {
        size_t j = idx - NPK_X - NPK_W;
        int o = (int)(j / KP);
        int k = (int)(j % KP);
        int c = k / WID, op = k % WID;
        float v = conv2_w[((size_t)(o * WID + op)) * CC + c];
        w2p[j] = f2bf(v);
    }
}

// ---------------- subject einsum via MFMA bf16: out[b,c,t] = sum_s x[b,c,s]*W[sid,t,s] + b_sub
// grid (8 t-tiles, 32 b), 256 thr = 4 waves; wave = 32c (2 m-tiles) x 64t (4 n-tiles)
__global__ __launch_bounds__(256) void k_einsum(const unsigned short* __restrict__ xb,
                                                const unsigned short* __restrict__ wb,
                                                const int* __restrict__ sid,
                                                const float* __restrict__ b_sub,
                                                float* __restrict__ oute) {
    int t0 = blockIdx.x * 64, b = blockIdx.y;
    int s = sid[b];
    int tid = threadIdx.x, w = tid >> 6, lr = tid & 15, lg = (tid >> 4) & 3;
    const unsigned short* A0 = xb + ((size_t)(b * 128 + w * 32 + lr)) * 512 + 8 * lg;
    const unsigned short* Bb = wb + (size_t)s * 262144 + 8 * lg;
    f32x4 acc[2][4] = {};
    for (int kb = 0; kb < 512; kb += 32) {
        BF8 a0, a1;
        a0.u = *(const u16x8*)(A0 + kb);
        a1.u = *(const u16x8*)(A0 + 16 * 512 + kb);
        #pragma unroll
        for (int nt = 0; nt < 4; nt++) {
            BF8 bf; bf.u = *(const u16x8*)(Bb + (size_t)(t0 + nt * 16 + lr) * 512 + kb);
            acc[0][nt] = __builtin_amdgcn_mfma_f32_16x16x32_bf16(a0.b, bf.b, acc[0][nt], 0, 0, 0);
            acc[1][nt] = __builtin_amdgcn_mfma_f32_16x16x32_bf16(a1.b, bf.b, acc[1][nt], 0, 0, 0);
        }
    }
    const float* bg = b_sub + (size_t)s * TT;
    #pragma unroll
    for (int nt = 0; nt < 4; nt++) {
        int t = t0 + nt * 16 + lr;
        if (t < TT) {
            float bias = bg[t];
            #pragma unroll
            for (int mt = 0; mt < 2; mt++) {
                int crow = w * 32 + mt * 16 + 4 * lg;
                #pragma unroll
                for (int r = 0; r < 4; r++) {
                    int c = crow + r;
                    if (c < CC) oute[((size_t)b * CC + c) * TT + t] = acc[mt][nt][r] + bias;
                }
            }
        }
    }
}

// ---------------- FIR21 stride5 + bn1 + elu -> p[b][t][c*80+o'] bf16 ----------------
__global__ __launch_bounds__(256, 2) void k_fir(const float* __restrict__ oute,
                                                const float* __restrict__ wc2,
                                                const float* __restrict__ b1f,
                                                unsigned short* __restrict__ p) {
    __shared__ float e_lds[TT];
    int c = blockIdx.x, b = blockIdx.y;
    int tid = threadIdx.x;
    if (tid < 125)
        ((float4*)e_lds)[tid] = ((const float4*)(oute + ((size_t)b * CC + c) * TT))[tid];
    __syncthreads();
    if (tid >= 240) return;
    int po = tid % WID, third = tid / WID;
    float wcr[21];
    #pragma unroll
    for (int d = 0; d < 21; d++) wcr[d] = wc2[po * 21 + d];
    float pbias = b1f[po];
    int tbase = third * 32;
    unsigned short* prow = p + ((size_t)b * TP) * KP + (size_t)c * WID + po;
    #pragma unroll 2
    for (int g = 0; g < 8; g++) {
        const float4* ep = (const float4*)(e_lds + tbase * 5 + 20 * g);
        float4 q0 = ep[0], q1 = ep[1], q2 = ep[2], q3 = ep[3], q4 = ep[4],
               q5 = ep[5], q6 = ep[6], q7 = ep[7], q8 = ep[8];
        float wv[36] = {q0.x,q0.y,q0.z,q0.w, q1.x,q1.y,q1.z,q1.w,
                        q2.x,q2.y,q2.z,q2.w, q3.x,q3.y,q3.z,q3.w,
                        q4.x,q4.y,q4.z,q4.w, q5.x,q5.y,q5.z,q5.w,
                        q6.x,q6.y,q6.z,q6.w, q7.x,q7.y,q7.z,q7.w,
                        q8.x,q8.y,q8.z,q8.w};
        #pragma unroll
        for (int j = 0; j < 4; j++) {
            float a = pbias;
            #pragma unroll
            for (int d = 0; d < 21; d++) a = fmaf(wcr[d], wv[5*j + d], a);
            a = eluf(a);
            prow[(size_t)(tbase + 4*g + j) * KP] = f2bf(a);
        }
    }
}

// ---------------- conv2 pure MFMA GEMM: part[ks][b][o][t] = sum_{k chunk} w2p[o,k] p[b,t,k]
__global__ __launch_bounds__(384) void k_conv2(const unsigned short* __restrict__ p,
                                               const unsigned short* __restrict__ w2p,
                                               float* __restrict__ part) {
    int chunk = blockIdx.x, b = blockIdx.y;
    int tid = threadIdx.x, w = tid >> 6, l = tid & 63, lr = l & 15, lg = l >> 4;
    int kb0 = (chunk * KBN) / KSPLIT;
    int kb1 = ((chunk + 1) * KBN) / KSPLIT;
    const unsigned short* Brow = p + ((size_t)(b * TP + w * 16 + lr)) * KP + 8 * lg;
    const unsigned short* Arow = w2p + (size_t)lr * KP + 8 * lg;
    f32x4 acc[5] = {};
    for (int kb = kb0; kb < kb1; kb++) {
        int ko = kb * 32;
        BF8 bf; bf.u = *(const u16x8*)(Brow + ko);
        #pragma unroll
        for (int mt = 0; mt < 5; mt++) {
            BF8 af; af.u = *(const u16x8*)(Arow + (size_t)mt * 16 * KP + ko);
            acc[mt] = __builtin_amdgcn_mfma_f32_16x16x32_bf16(af.b, bf.b, acc[mt], 0, 0, 0);
        }
    }
    float* pp = part + ((size_t)(chunk * BB + b) * WID) * TP;
    int t = w * 16 + lr;
    #pragma unroll
    for (int mt = 0; mt < 5; mt++) {
        int ob = mt * 16 + 4 * lg;
        #pragma unroll
        for (int r = 0; r < 4; r++)
            pp[(size_t)(ob + r) * TP + t] = acc[mt][r];
    }
}

// ---------------- reduce split-K + bn2 + elu (y2 stays in LDS) + proj -> z_bf ----------------
__global__ __launch_bounds__(256) void k_redproj(const float* __restrict__ part,
                                                 const float* __restrict__ scale2,
                                                 const float* __restrict__ shift2f,
                                                 const float* __restrict__ pw,
                                                 const float* __restrict__ pb,
                                                 unsigned short* __restrict__ zbf) {
    __shared__ float ly[WID * TP];   // 7680
    __shared__ float lw[EMB * WID];  // 640
    int b = blockIdx.x, tid = threadIdx.x;
    for (int i = tid; i < EMB * WID; i += 256) lw[i] = pw[i];
    for (int i = tid; i < WID * TP; i += 256) {
        float acc = 0.f;
        #pragma unroll
        for (int ks = 0; ks < KSPLIT; ks++)
            acc += part[(size_t)(ks * BB + b) * (WID * TP) + i];
        int o = i / TP;
        ly[i] = eluf(acc * scale2[o] + shift2f[o]);
    }
    __syncthreads();
    #pragma unroll
    for (int rep = 0; rep < 3; rep++) {
        int j = tid + 256 * rep;
        int e = j & 7, t = j >> 3;
        float acc = pb[e];
        #pragma unroll 10
        for (int o = 0; o < WID; o++) acc = fmaf(ly[o * TP + t], lw[e * WID + o], acc);
        zbf[(size_t)b * HID + j] = f2bf(acc);
    }
}

// ---------------- mlp1 batch-shared MFMA: z1[32,1024] = Zbf @ W1^T + b; g_bf = gelu(z1)
// grid 16 blocks (64 p-cols each), 4 waves; wave = 16 p-cols x both 16-row m-tiles.
// Weights read ONCE (fp32->bf16 inline), vs 32x re-read in the old per-batch version.
__global__ __launch_bounds__(256) void k_mlp1(const unsigned short* __restrict__ zbf,
                                              const float* __restrict__ w1,
                                              const float* __restrict__ bias,
                                              float* __restrict__ z1,
                                              unsigned short* __restrict__ gbf) {
    int n0 = blockIdx.x * 64;
    int tid = threadIdx.x, w = tid >> 6, lr = tid & 15, lg = (tid >> 4) & 3;
    int pcol = n0 + w * 16 + lr;
    const float* wr = w1 + (size_t)pcol * HID + 8 * lg;
    const unsigned short* za = zbf + (size_t)lr * HID + 8 * lg;
    f32x4 acc[2] = {};
    for (int kb = 0; kb < HID; kb += 32) {
        float4 w0 = *(const float4*)(wr + kb);
        float4 w1v = *(const float4*)(wr + kb + 4);
        BF8 bf;
        bf.u[0] = f2bf(w0.x); bf.u[1] = f2bf(w0.y); bf.u[2] = f2bf(w0.z); bf.u[3] = f2bf(w0.w);
        bf.u[4] = f2bf(w1v.x); bf.u[5] = f2bf(w1v.y); bf.u[6] = f2bf(w1v.z); bf.u[7] = f2bf(w1v.w);
        BF8 a0, a1;
        a0.u = *(const u16x8*)(za + kb);
        a1.u = *(const u16x8*)(za + (size_t)16 * HID + kb);
        acc[0] = __builtin_amdgcn_mfma_f32_16x16x32_bf16(a0.b, bf.b, acc[0], 0, 0, 0);
        acc[1] = __builtin_amdgcn_mfma_f32_16x16x32_bf16(a1.b, bf.b, acc[1], 0, 0, 0);
    }
    float bs = bias[pcol];
    #pragma unroll
    for (int mt = 0; mt < 2; mt++) {
        #pragma unroll
        for (int r = 0; r < 4; r++) {
            int bb = mt * 16 + 4 * lg + r;
            float v = acc[mt][r] + bs;
            z1[(size_t)bb * PROJ + pcol] = v;
            float g = 0.5f * v * (1.f + erff(v * 0.70710678118654752f));
            gbf[(size_t)bb * PROJ + pcol] = f2bf(g);
        }
    }
}

// ---------------- mlp2 batch-shared MFMA + residual: y = z1 + Gbf @ W2^T + b2
__global__ __launch_bounds__(256) void k_mlp2(const unsigned short* __restrict__ gbf,
                                              const float* __restrict__ z1,
                                              const float* __restrict__ w2,
                                              const float* __restrict__ bias,
                                              float* __restrict__ y) {
    int n0 = blockIdx.x * 64;
    int tid = threadIdx.x, w = tid >> 6, lr = tid & 15, lg = (tid >> 4) & 3;
    int q = n0 + w * 16 + lr;
    const float* wr = w2 + (size_t)q * PROJ + 8 * lg;
    const unsigned short* ga = gbf + (size_t)lr * PROJ + 8 * lg;
    f32x4 acc[2] = {};
    for (int kb = 0; kb < PROJ; kb += 32) {
        float4 w0 = *(const float4*)(wr + kb);
        float4 w1v = *(const float4*)(wr + kb + 4);
        BF8 bf;
        bf.u[0] = f2bf(w0.x); bf.u[1] = f2bf(w0.y); bf.u[2] = f2bf(w0.z); bf.u[3] = f2bf(w0.w);
        bf.u[4] = f2bf(w1v.x); bf.u[5] = f2bf(w1v.y); bf.u[6] = f2bf(w1v.z); bf.u[7] = f2bf(w1v.w);
        BF8 a0, a1;
        a0.u = *(const u16x8*)(ga + kb);
        a1.u = *(const u16x8*)(ga + (size_t)16 * PROJ + kb);
        acc[0] = __builtin_amdgcn_mfma_f32_16x16x32_bf16(a0.b, bf.b, acc[0], 0, 0, 0);
        acc[1] = __builtin_amdgcn_mfma_f32_16x16x32_bf16(a1.b, bf.b, acc[1], 0, 0, 0);
    }
    float bs = bias[q];
    #pragma unroll
    for (int mt = 0; mt < 2; mt++) {
        #pragma unroll
        for (int r = 0; r < 4; r++) {
            int bb = mt * 16 + 4 * lg + r;
            y[(size_t)bb * PROJ + q] = z1[(size_t)bb * PROJ + q] + acc[mt][r] + bs;
        }
    }
}

// ---------------- LayerNorm over 1024 per row -> d_out
__global__ __launch_bounds__(256) void k_ln(const float* __restrict__ y,
                                            const float* __restrict__ lg,
                                            const float* __restrict__ lb,
                                            float* __restrict__ out) {
    int b = blockIdx.x, tid = threadIdx.x;
    const float4* yr = (const float4*)(y + (size_t)b * PROJ);
    float4 v = yr[tid];
    float s  = v.x + v.y + v.z + v.w;
    float sq = v.x*v.x + v.y*v.y + v.z*v.z + v.w*v.w;
    #pragma unroll
    for (int off = 32; off > 0; off >>= 1) {
        s  += __shfl_down(s, off);
        sq += __shfl_down(sq, off);
    }
    __shared__ float ss[4], ssq[4];
    int wv = tid >> 6, lane = tid & 63;
    if (lane == 0) { ss[wv] = s; ssq[wv] = sq; }
    __syncthreads();
    __shared__ float smu, sinv;
    if (tid == 0) {
        float Sm = ss[0] + ss[1] + ss[2] + ss[3];
        float Sq = ssq[0] + ssq[1] + ssq[2] + ssq[3];
        float mu = Sm * (1.f / PROJ);
        float var = Sq * (1.f / PROJ) - mu * mu;
        smu = mu;
        sinv = rsqrtf(var + EPSF);
    }
    __syncthreads();
    float mu = smu, inv = sinv;
    float4 g4 = ((const float4*)lg)[tid];
    float4 b4 = ((const float4*)lb)[tid];
    float4 o4;
    o4.x = (v.x - mu) * inv * g4.x + b4.x;
    o4.y = (v.y - mu) * inv * g4.y + b4.y;
    o4.z = (v.z - mu) * inv * g4.z + b4.z;
    o4.w = (v.w - mu) * inv * g4.w + b4.w;
    ((float4*)(out + (size_t)b * PROJ))[tid] = o4;
}

extern "C" void kernel_launch(void* const* d_in, const int* in_sizes, int n_in,
                              void* d_out, int out_size, void* d_ws, size_t ws_size,
                              hipStream_t stream) {
    const float* x        = (const float*)d_in[0];
    const int*   sid      = (const int*)  d_in[1];
    const float* W_sub    = (const float*)d_in[2];
    const float* b_sub    = (const float*)d_in[3];
    const float* conv1_w  = (const float*)d_in[4];
    const float* conv1_b  = (const float*)d_in[5];
    const float* bn1_g    = (const float*)d_in[6];
    const float* bn1_b    = (const float*)d_in[7];
    const float* bn1_m    = (const float*)d_in[8];
    const float* bn1_v    = (const float*)d_in[9];
    const float* conv2_w  = (const float*)d_in[10];
    const float* conv2_b  = (const float*)d_in[11];
    const float* bn2_g    = (const float*)d_in[12];
    const float* bn2_b    = (const float*)d_in[13];
    const float* bn2_m    = (const float*)d_in[14];
    const float* bn2_v    = (const float*)d_in[15];
    const float* proj_w   = (const float*)d_in[16];
    const float* proj_b   = (const float*)d_in[17];
    const float* mlp1_w   = (const float*)d_in[18];
    const float* mlp1_b   = (const float*)d_in[19];
    const float* mlp2_w   = (const float*)d_in[20];
    const float* mlp2_b   = (const float*)d_in[21];
    const float* ln_g     = (const float*)d_in[22];
    const float* ln_b     = (const float*)d_in[23];
    float* out = (float*)d_out;
    float* ws  = (float*)d_ws;

    float* ws_e    = ws + OFF_E;
    unsigned short* ws_xb  = (unsigned short*)(ws + OFF_XB);
    unsigned short* ws_wb  = (unsigned short*)(ws + OFF_WB);
    unsigned short* ws_w2p = (unsigned short*)(ws + OFF_W2P);
    unsigned short* ws_p   = (unsigned short*)(ws + OFF_P);
    float* ws_part = ws + OFF_PART;
    unsigned short* ws_zbf = (unsigned short*)(ws + OFF_Z);
    float* ws_z1   = ws + OFF_Z1;
    unsigned short* ws_gbf = (unsigned short*)(ws + OFF_G);
    float* ws_y    = ws + OFF_Y;
    float* ws_wc   = ws + OFF_WC;
    float* ws_b1f  = ws + OFF_B1F;
    float* ws_sc2  = ws + OFF_SC2;
    float* ws_sh2  = ws + OFF_SH2;

    hipLaunchKernelGGL(k_pack, dim3((NPK_TOT + 255) / 256), dim3(256), 0, stream,
                       x, W_sub, conv2_w,
                       conv1_w, conv1_b, bn1_g, bn1_b, bn1_m, bn1_v,
                       conv2_b, bn2_g, bn2_b, bn2_m, bn2_v,
                       ws_xb, ws_wb, ws_w2p,
                       ws_wc, ws_b1f, ws_sc2, ws_sh2);

    hipLaunchKernelGGL(k_einsum, dim3(8, BB), dim3(256), 0, stream,
                       ws_xb, ws_wb, sid, b_sub, ws_e);

    hipLaunchKernelGGL(k_fir, dim3(CC, BB), dim3(256), 0, stream,
                       ws_e, ws_wc, ws_b1f, ws_p);

    hipLaunchKernelGGL(k_conv2, dim3(KSPLIT, BB), dim3(384), 0, stream,
                       ws_p, ws_w2p, ws_part);

    hipLaunchKernelGGL(k_redproj, dim3(BB), dim3(256), 0, stream,
                       ws_part, ws_sc2, ws_sh2, proj_w, proj_b, ws_zbf);

    hipLaunchKernelGGL(k_mlp1, dim3(PROJ / 64), dim3(256), 0, stream,
                       ws_zbf, mlp1_w, mlp1_b, ws_z1, ws_gbf);

    hipLaunchKernelGGL(k_mlp2, dim3(PROJ / 64), dim3(256), 0, stream,
                       ws_gbf, ws_z1, mlp2_w, mlp2_b, ws_y);

    hipLaunchKernelGGL(k_ln, dim3(BB), dim3(256), 0, stream,
                       ws_y, ln_g, ln_b, out);
}